// Round 18
// baseline (252.730 us; speedup 1.0000x reference)
//
#include <hip/hip_runtime.h>
#include <cstdint>
#include <cstddef>

#define N_NODES 30000
#define E_EDGES 480000
#define ETOT    510000   // E + N self-loops
#define IN_DIM  128
#define HID     256
#define HEADS   4
#define NEG_SLOPE 0.2f
#define DEG_BLOCKS 1993  // cdiv(ETOT,256)

static inline int cdiv(int a, int b){ return (a + b - 1) / b; }

typedef short bf16x8 __attribute__((ext_vector_type(8)));
typedef float f32x4  __attribute__((ext_vector_type(4)));
typedef float f32x2  __attribute__((ext_vector_type(2)));

__device__ __forceinline__ unsigned short f2bf(float f) {
  unsigned u = __float_as_uint(f);
  unsigned r = (u + 0x7FFFu + ((u >> 16) & 1u)) >> 16;   // RNE
  return (unsigned short)r;
}
__device__ __forceinline__ float bf2f(unsigned short s) {
  return __uint_as_float((unsigned)s << 16);
}
// fp8 e4m3 (OCP on gfx950) encode: low byte of packed pair
__device__ __forceinline__ unsigned char f2fp8(float v) {
  return (unsigned char)(__builtin_amdgcn_cvt_pk_fp8_f32(v, v, 0, false) & 0xFF);
}
// async global->LDS, 16B per lane (width-16 verified m97)
__device__ __forceinline__ void gload_lds16(const void* g, void* l) {
  __builtin_amdgcn_global_load_lds(
      (const __attribute__((address_space(1))) void*)g,
      (__attribute__((address_space(3))) void*)l, 16, 0, 0);
}

// ---- zero deg[30720] via int4 stores ----
__global__ __launch_bounds__(256) void zero_deg(int4* __restrict__ deg4)
{
  deg4[blockIdx.x * 256 + threadIdx.x] = int4{0, 0, 0, 0};
}

// ---- setup: deg_count (blocks 0..1992) + x->bf16 + W transposes ----
__global__ __launch_bounds__(256) void setup(
    const int* __restrict__ ei, int* __restrict__ deg,
    const float* __restrict__ x, const float* __restrict__ W1,
    const float* __restrict__ Wp, const float* __restrict__ W2,
    ushort* __restrict__ xbf, ushort* __restrict__ w1t,
    ushort* __restrict__ wpt, ushort* __restrict__ w2t)
{
  int b = blockIdx.x;
  int t = threadIdx.x;
  if (b < DEG_BLOCKS) {
    int e = b * 256 + t;
    if (e < ETOT) {
      int d = (e < E_EDGES) ? ei[E_EDGES + e] : (e - E_EDGES);
      atomicAdd(&deg[d], 1);
    }
    return;
  }
  b -= DEG_BLOCKS;
  if (b < 3750) {                       // 3750*256*4 = N*IN
    int i = b * 256 + t;
    float4 v = ((const float4*)x)[i];
    ushort4 o;
    o.x = f2bf(v.x); o.y = f2bf(v.y); o.z = f2bf(v.z); o.w = f2bf(v.w);
    ((ushort4*)xbf)[i] = o;
  } else if (b < 3750 + 128) {
    int k = b - 3750;
    w1t[(size_t)t * IN_DIM + k] = f2bf(W1[(size_t)k * HID + t]);
  } else if (b < 3750 + 256) {
    int k = b - 3878;
    wpt[(size_t)t * IN_DIM + k] = f2bf(Wp[(size_t)k * HID + t]);
  } else {
    int k = b - 4006;
    w2t[(size_t)t * HID + k] = f2bf(W2[(size_t)k * HID + t]);
  }
}

// ================= CSR rowptr scan: shfl wave-scan, 2 syncthreads =================
__global__ __launch_bounds__(1024) void scan_rowptr(const int* __restrict__ deg,
                                                    int* __restrict__ rowptr,
                                                    int* __restrict__ cursor)
{
  const int CE = 30;
  __shared__ int wtot[16];
  __shared__ int wexc[16];
  int t = threadIdx.x;
  int wv = t >> 6, lane = t & 63;
  int base = t * CE;
  int local[CE];
  int s = 0;
  #pragma unroll
  for (int i = 0; i < CE; ++i) {
    int idx = base + i;
    int v = (idx < N_NODES) ? deg[idx] : 0;
    local[i] = s;
    s += v;
  }
  int incl = s;                          // inclusive 64-lane scan
  #pragma unroll
  for (int off = 1; off < 64; off <<= 1) {
    int v = __shfl_up(incl, off);
    if (lane >= off) incl += v;
  }
  if (lane == 63) wtot[wv] = incl;
  __syncthreads();
  if (t < 16) {
    int v = wtot[t];
    int inc2 = v;
    #pragma unroll
    for (int off = 1; off < 16; off <<= 1) {
      int u = __shfl_up(inc2, off);
      if (t >= off) inc2 += u;
    }
    wexc[t] = inc2 - v;
  }
  __syncthreads();
  int off0 = wexc[wv] + (incl - s);      // exclusive thread offset
  #pragma unroll
  for (int i = 0; i < CE; ++i) {
    int idx = base + i;
    if (idx < N_NODES) {
      rowptr[idx] = off0 + local[i];
      cursor[idx] = off0 + local[i];
    }
  }
  if (t == 1023) rowptr[N_NODES] = off0 + s;
}

// ---- standalone edge scatter (low VGPR -> high occupancy for atomic latency) ----
__global__ __launch_bounds__(256) void scatter_edges(const int* __restrict__ ei,
                                                     int* __restrict__ cursor,
                                                     int* __restrict__ col)
{
  int e = blockIdx.x * blockDim.x + threadIdx.x;
  if (e >= ETOT) return;
  int s, d;
  if (e < E_EDGES) { s = ei[e]; d = ei[E_EDGES + e]; }
  else             { s = d = e - E_EDGES; }
  int pos = atomicAdd(&cursor[d], 1);
  col[pos] = s;
}

// ---- LDS-staged bf16 MFMA GEMM (m97-lite) + attn-logit epilogue (+L1 proj) ----
template<int K, bool L1>
__global__ __launch_bounds__(256) void gemm_lds(
    const ushort* __restrict__ A,    // [n][K] bf16
    const ushort* __restrict__ WT,   // [NOUT][K] bf16 (W1t|Wpt contiguous for L1)
    const float* __restrict__ att_src, const float* __restrict__ att_dst,
    unsigned char* __restrict__ hout, float* __restrict__ esrc,
    float* __restrict__ edst, ushort* __restrict__ rout,
    const float* __restrict__ pbias, int n)
{
  __shared__ ushort As[128 * 32];       // [row][pos] 64B/row, 8KB
  __shared__ ushort Bs[128 * 32];
  const int t = threadIdx.x;
  const int wv = t >> 6;
  const int lane = t & 63;
  const int wr = wv >> 1, wc = wv & 1;
  const int brow = blockIdx.x * 128;
  const int bcol0 = blockIdx.y * 128;
  const int lrow = lane & 15;
  const int kgrp = lane >> 4;           // 0..3

  // staging geometry: chunk = wv*128 + i*64 + lane (16B each); row=chunk>>2, pos=chunk&3
  int sc_row[2], sc_kc[2];
  #pragma unroll
  for (int i = 0; i < 2; ++i) {
    int chunk = wv * 128 + i * 64 + lane;
    sc_row[i] = chunk >> 2;
    sc_kc[i] = (chunk & 3) ^ (sc_row[i] & 3);   // pre-swizzled source k-chunk
  }

  f32x4 acc[4][4] = {};
  for (int k0 = 0; k0 < K; k0 += 32) {
    #pragma unroll
    for (int i = 0; i < 2; ++i) {
      int ar = min(brow + sc_row[i], n - 1);
      gload_lds16(&A[(size_t)ar * K + k0 + sc_kc[i] * 8],
                  &As[(size_t)(wv * 2 + i) * 512]);
      int bc = bcol0 + sc_row[i];
      gload_lds16(&WT[(size_t)bc * K + k0 + sc_kc[i] * 8],
                  &Bs[(size_t)(wv * 2 + i) * 512]);
    }
    __syncthreads();                    // drains vmcnt+lgkmcnt (compiler-inserted)
    bf16x8 a[4], b[4];
    #pragma unroll
    for (int mi = 0; mi < 4; ++mi) {
      int tr = wr * 64 + mi * 16 + lrow;
      int pos = kgrp ^ (tr & 3);
      a[mi] = *(const bf16x8*)&As[tr * 32 + pos * 8];
    }
    #pragma unroll
    for (int ni = 0; ni < 4; ++ni) {
      int tc = wc * 64 + ni * 16 + lrow;
      int pos = kgrp ^ (tc & 3);
      b[ni] = *(const bf16x8*)&Bs[tc * 32 + pos * 8];
    }
    #pragma unroll
    for (int mi = 0; mi < 4; ++mi)
      #pragma unroll
      for (int ni = 0; ni < 4; ++ni)
        acc[mi][ni] = __builtin_amdgcn_mfma_f32_16x16x32_bf16(a[mi], b[ni], acc[mi][ni], 0, 0, 0);
    __syncthreads();                    // before restage
  }

  const int bcol = bcol0 + wc * 64;
  const bool proj = L1 && (bcol >= 256);
  // C write (C/D layout: col=lane&15, row=(lane>>4)*4+reg — m89-verified)
  const int browt = brow + wr * 64;
  #pragma unroll
  for (int mi = 0; mi < 4; ++mi) {
    #pragma unroll
    for (int r = 0; r < 4; ++r) {
      int row = browt + mi * 16 + kgrp * 4 + r;
      if (row < n) {
        #pragma unroll
        for (int ni = 0; ni < 4; ++ni) {
          int colg = bcol + ni * 16 + lrow;
          float v = acc[mi][ni][r];
          if (proj) {
            int c = colg - 256;
            rout[(size_t)row * HID + c] = f2bf(v + pbias[c]);
          } else {
            hout[(size_t)row * HID + colg] = f2fp8(v);
          }
        }
      }
    }
  }
  // fused attention-logit epilogue: wave's 64 cols == head (bcol>>6)
  if (!proj) {
    const int hh = bcol >> 6;
    float as[4], ad[4];
    #pragma unroll
    for (int ni = 0; ni < 4; ++ni) {
      as[ni] = att_src[hh * 64 + ni * 16 + lrow];
      ad[ni] = att_dst[hh * 64 + ni * 16 + lrow];
    }
    #pragma unroll
    for (int mi = 0; mi < 4; ++mi) {
      #pragma unroll
      for (int r = 0; r < 4; ++r) {
        float vs = 0.f, vd = 0.f;
        #pragma unroll
        for (int ni = 0; ni < 4; ++ni) {
          float c = acc[mi][ni][r];
          vs += c * as[ni];
          vd += c * ad[ni];
        }
        #pragma unroll
        for (int m = 1; m <= 8; m <<= 1) {
          vs += __shfl_xor(vs, m);
          vd += __shfl_xor(vd, m);
        }
        int row = browt + mi * 16 + kgrp * 4 + r;
        if (lrow == 0 && row < n) {
          esrc[row * HEADS + hh] = vs;
          edst[row * HEADS + hh] = vd;
        }
      }
    }
  }
}

// ========== aggregation: one 16-LANE GROUP per dst node, A/B-pipelined chunks ==========
// __launch_bounds__(256,3): ~168 VGPR so TWO 8-edge gather windows (2x(8 col +
// 8 esrc + 8x16B h)) stay in flight. Chunk k+1's loads issue BEFORE chunk k's
// compute -> all but the first gather-latency round hide under VALU.
// Tail chunk is a masked pipeline stage (no serial epilogue).
#define AGG_LOADF(base, S, ES, W)                                        \
  do {                                                                   \
    _Pragma("unroll") for (int i = 0; i < 8; ++i) S[i] = col[(base) + i];\
    _Pragma("unroll") for (int i = 0; i < 8; ++i)                        \
      ES[i] = esrc[S[i] * HEADS + headc];                                \
    _Pragma("unroll") for (int i = 0; i < 8; ++i)                        \
      W[i] = *(const uint4*)&h8[(size_t)S[i] * HID + cblk];              \
  } while (0)
#define AGG_LOADM(base, S, ES, W)                                        \
  do {                                                                   \
    _Pragma("unroll") for (int i = 0; i < 8; ++i)                        \
      S[i] = col[min((base) + i, r1 - 1)];                               \
    _Pragma("unroll") for (int i = 0; i < 8; ++i)                        \
      ES[i] = esrc[S[i] * HEADS + headc];                                \
    _Pragma("unroll") for (int i = 0; i < 8; ++i)                        \
      W[i] = *(const uint4*)&h8[(size_t)S[i] * HID + cblk];              \
  } while (0)
#define AGG_COMP(ES, W, PV)                                              \
  do {                                                                   \
    _Pragma("unroll") for (int i = 0; i < 8; ++i) {                      \
      float vv = ES[i] + edh;                                            \
      vv = (vv >= 0.f) ? vv : NEG_SLOPE * vv;                            \
      float p = PV;                                                      \
      dp += p;                                                           \
      f32x2 p2 = { p, p };                                               \
      unsigned wd0 = W[i].x, wd1 = W[i].y, wd2 = W[i].z, wd3 = W[i].w;   \
      acc2[0] += __builtin_amdgcn_cvt_pk_f32_fp8(wd0, false) * p2;       \
      acc2[1] += __builtin_amdgcn_cvt_pk_f32_fp8(wd0, true)  * p2;       \
      acc2[2] += __builtin_amdgcn_cvt_pk_f32_fp8(wd1, false) * p2;       \
      acc2[3] += __builtin_amdgcn_cvt_pk_f32_fp8(wd1, true)  * p2;       \
      acc2[4] += __builtin_amdgcn_cvt_pk_f32_fp8(wd2, false) * p2;       \
      acc2[5] += __builtin_amdgcn_cvt_pk_f32_fp8(wd2, true)  * p2;       \
      acc2[6] += __builtin_amdgcn_cvt_pk_f32_fp8(wd3, false) * p2;       \
      acc2[7] += __builtin_amdgcn_cvt_pk_f32_fp8(wd3, true)  * p2;       \
    }                                                                    \
  } while (0)

template<bool WRITE_BF16>
__global__ __launch_bounds__(256, 3) void gat_agg(
    const int* __restrict__ rowptr, const int* __restrict__ col,
    const float* __restrict__ esrc, const float* __restrict__ edst,
    const unsigned char* __restrict__ h8, const float* __restrict__ bias,
    const ushort* __restrict__ resid, const float* __restrict__ gamma,
    const float* __restrict__ beta, float* __restrict__ out_f32,
    ushort* __restrict__ out_bf16)
{
  const int t = threadIdx.x;
  const int lane16 = t & 15;                   // channel sub-block within group
  const int d = blockIdx.x * 16 + (t >> 4);    // grid = 1875 exact
  const int cblk = lane16 * 16;                // 16 fp8 channels
  const int headc = lane16 >> 2;               // head of these channels
  const int r0 = rowptr[d], r1 = rowptr[d + 1];

  // hoisted independent loads (overlap under the gather loop)
  const uint4* rp = (const uint4*)&resid[(size_t)d * HID + cblk];
  uint4 r0v = rp[0], r1v = rp[1];
  const float edh = edst[d * HEADS + headc];

  f32x2 acc2[8] = {};                          // 16 channels
  float dp = 0.f;

  const int deg = r1 - r0;
  const int nc = (deg + 7) >> 3;               // chunks; last may be partial
  int sA[8], sB[8];
  float eA[8], eB[8];
  uint4 wA[8], wB[8];

  if (nc == 1) {
    int jb = r0;
    AGG_LOADM(jb, sA, eA, wA);
    AGG_COMP(eA, wA, (jb + i < r1) ? __expf(vv) : 0.f);
  } else if (nc > 1) {
    AGG_LOADF(r0, sA, eA, wA);                 // stage chunk 0
    int c = 1;
    for (; c < nc - 1; ++c) {                  // middle full chunks, ping-pong
      int base = r0 + 8 * c;
      if (c & 1) { AGG_LOADF(base, sB, eB, wB); AGG_COMP(eA, wA, __expf(vv)); }
      else       { AGG_LOADF(base, sA, eA, wA); AGG_COMP(eB, wB, __expf(vv)); }
    }
    int jb = r0 + 8 * (nc - 1);                // last (masked) chunk
    if ((nc - 1) & 1) {
      AGG_LOADM(jb, sB, eB, wB);
      AGG_COMP(eA, wA, __expf(vv));
      AGG_COMP(eB, wB, (jb + i < r1) ? __expf(vv) : 0.f);
    } else {
      AGG_LOADM(jb, sA, eA, wA);
      AGG_COMP(eB, wB, __expf(vv));
      AGG_COMP(eA, wA, (jb + i < r1) ? __expf(vv) : 0.f);
    }
  }

  float rden = 1.f / dp;                       // per-head denom, group-uniform

  // v = agg/den + bias + resid (16 channels per lane)
  f32x2 v2[8];
  {
    unsigned rd[8] = { r0v.x, r0v.y, r0v.z, r0v.w, r1v.x, r1v.y, r1v.z, r1v.w };
    const f32x2* b2 = (const f32x2*)&bias[cblk];
    f32x2 rden2 = { rden, rden };
    #pragma unroll
    for (int q = 0; q < 8; ++q) {
      f32x2 rw;
      rw.x = __uint_as_float(rd[q] << 16);
      rw.y = __uint_as_float(rd[q] & 0xffff0000u);
      v2[q] = acc2[q] * rden2 + b2[q] + rw;
    }
  }

  // LayerNorm stats over the 16-lane group (each channel once) -> /256
  float s1 = 0.f, s2 = 0.f;
  #pragma unroll
  for (int q = 0; q < 8; ++q) {
    s1 += v2[q].x + v2[q].y;
    s2 += v2[q].x * v2[q].x + v2[q].y * v2[q].y;
  }
  #pragma unroll
  for (int m = 1; m <= 8; m <<= 1) {
    s1 += __shfl_xor(s1, m);
    s2 += __shfl_xor(s2, m);
  }
  float mu = s1 * (1.f / HID);
  float var = s2 * (1.f / HID) - mu * mu;
  float rr = rsqrtf(var + 1e-5f);

  const f32x2* g2 = (const f32x2*)&gamma[cblk];
  const f32x2* e2 = (const f32x2*)&beta[cblk];
  float y[16];
  #pragma unroll
  for (int q = 0; q < 8; ++q) {
    f32x2 g = g2[q], e = e2[q];
    float t0 = (v2[q].x - mu) * rr * g.x + e.x;
    float t1 = (v2[q].y - mu) * rr * g.y + e.y;
    y[2 * q]     = (t0 > 0.f) ? t0 : expm1f(t0);
    y[2 * q + 1] = (t1 > 0.f) ? t1 : expm1f(t1);
  }
  if (WRITE_BF16) {
    uint4 o[2];
    #pragma unroll
    for (int q = 0; q < 8; ++q) {
      unsigned wv = (unsigned)f2bf(y[2 * q]) | ((unsigned)f2bf(y[2 * q + 1]) << 16);
      ((unsigned*)o)[q] = wv;
    }
    uint4* op = (uint4*)&out_bf16[(size_t)d * HID + cblk];
    op[0] = o[0]; op[1] = o[1];
  } else {
    float4* op = (float4*)&out_f32[(size_t)d * HID + cblk];
    #pragma unroll
    for (int q = 0; q < 4; ++q) {
      float4 ov = { y[4 * q], y[4 * q + 1], y[4 * q + 2], y[4 * q + 3] };
      op[q] = ov;
    }
  }
}

extern "C" void kernel_launch(void* const* d_in, const int* in_sizes, int n_in,
                              void* d_out, int out_size, void* d_ws, size_t ws_size,
                              hipStream_t stream) {
  const float* x   = (const float*)d_in[0];
  const int*   ei  = (const int*)d_in[1];
  const float* W1  = (const float*)d_in[2];
  const float* as1 = (const float*)d_in[3];
  const float* ad1 = (const float*)d_in[4];
  const float* b1  = (const float*)d_in[5];
  const float* W2  = (const float*)d_in[6];
  const float* as2 = (const float*)d_in[7];
  const float* ad2 = (const float*)d_in[8];
  const float* b2  = (const float*)d_in[9];
  const float* g1  = (const float*)d_in[10];
  const float* be1 = (const float*)d_in[11];
  const float* g2  = (const float*)d_in[12];
  const float* be2 = (const float*)d_in[13];
  const float* Wp  = (const float*)d_in[14];
  const float* bp  = (const float*)d_in[15];
  float* out = (float*)d_out;

  const size_t NB16 = (size_t)N_NODES * HID * sizeof(ushort);  // 15.36 MB
  const size_t NB8  = (size_t)N_NODES * HID;                   // 7.68 MB (fp8)
  const size_t XB16 = (size_t)N_NODES * IN_DIM * sizeof(ushort);
  const size_t NH_BUF = (size_t)N_NODES * HEADS * sizeof(float);
  char* ws = (char*)d_ws;
  size_t off = 0;
  unsigned char* h8 = (unsigned char*)(ws + off); off += NB8;  // h gather table (fp8)
  ushort* hAbf  = (ushort*)(ws + off); off += NB16;            // hA / layer-2 resid
  ushort* rbf   = (ushort*)(ws + off); off += NB16;            // layer-1 resid (bf16)
  ushort* xbf   = (ushort*)(ws + off); off += XB16;
  ushort* w1t   = (ushort*)(ws + off); off += (size_t)HID * IN_DIM * 2;  // [w1t|wpt]
  ushort* wpt   = (ushort*)(ws + off); off += (size_t)HID * IN_DIM * 2;
  ushort* w2t   = (ushort*)(ws + off); off += (size_t)HID * HID * 2;
  float*  esrc  = (float*) (ws + off); off += NH_BUF;
  float*  edstb = (float*) (ws + off); off += NH_BUF;
  int*    deg    = (int*)(ws + off); off += (size_t)30720 * 4;  // padded for int4 zero
  int*    rowptr = (int*)(ws + off); off += (size_t)(N_NODES + 1) * 4;
  int*    cursor = (int*)(ws + off); off += (size_t)N_NODES * 4;
  int*    col    = (int*)(ws + off); off += (size_t)ETOT * 4;

  // ---- CSR build + precision prep ----
  zero_deg<<<30, 256, 0, stream>>>((int4*)deg);
  setup<<<DEG_BLOCKS + 3750 + 128 + 128 + 256, 256, 0, stream>>>(
      ei, deg, x, W1, Wp, W2, xbf, w1t, wpt, w2t);
  scan_rowptr<<<1, 1024, 0, stream>>>(deg, rowptr, cursor);
  scatter_edges<<<cdiv(ETOT, 256), 256, 0, stream>>>(ei, cursor, col);

  // ================= Layer 1 (W1 and Wp fused: 512 output cols) =================
  gemm_lds<IN_DIM, true><<<dim3(cdiv(N_NODES, 128), 4), 256, 0, stream>>>(
      xbf, w1t, as1, ad1, h8, esrc, edstb, rbf, bp, N_NODES);
  gat_agg<true><<<N_NODES / 16, 256, 0, stream>>>(
      rowptr, col, esrc, edstb, h8, b1, rbf, g1, be1, nullptr, hAbf);

  // ================= Layer 2 =================
  gemm_lds<HID, false><<<dim3(cdiv(N_NODES, 128), 2), 256, 0, stream>>>(
      hAbf, w2t, as2, ad2, h8, esrc, edstb, nullptr, nullptr, N_NODES);
  gat_agg<false><<<N_NODES / 16, 256, 0, stream>>>(
      rowptr, col, esrc, edstb, h8, b2, hAbf, g2, be2, out, nullptr);
}

// Round 19
// 201.345 us; speedup vs baseline: 1.2552x; 1.2552x over previous
//
#include <hip/hip_runtime.h>
#include <cstdint>
#include <cstddef>

#define N_NODES 30000
#define E_EDGES 480000
#define ETOT    510000   // E + N self-loops
#define IN_DIM  128
#define HID     256
#define HEADS   4
#define NEG_SLOPE 0.2f
#define DEG_BLOCKS 1993  // cdiv(ETOT,256)

static inline int cdiv(int a, int b){ return (a + b - 1) / b; }

typedef short bf16x8 __attribute__((ext_vector_type(8)));
typedef float f32x4  __attribute__((ext_vector_type(4)));
typedef float f32x2  __attribute__((ext_vector_type(2)));

__device__ __forceinline__ unsigned short f2bf(float f) {
  unsigned u = __float_as_uint(f);
  unsigned r = (u + 0x7FFFu + ((u >> 16) & 1u)) >> 16;   // RNE
  return (unsigned short)r;
}
__device__ __forceinline__ float bf2f(unsigned short s) {
  return __uint_as_float((unsigned)s << 16);
}
// fp8 e4m3 (OCP on gfx950) encode: low byte of packed pair
__device__ __forceinline__ unsigned char f2fp8(float v) {
  return (unsigned char)(__builtin_amdgcn_cvt_pk_fp8_f32(v, v, 0, false) & 0xFF);
}
// async global->LDS, 16B per lane (width-16 verified m97)
__device__ __forceinline__ void gload_lds16(const void* g, void* l) {
  __builtin_amdgcn_global_load_lds(
      (const __attribute__((address_space(1))) void*)g,
      (__attribute__((address_space(3))) void*)l, 16, 0, 0);
}

// ---- zero deg[30720] via int4 stores ----
__global__ __launch_bounds__(256) void zero_deg(int4* __restrict__ deg4)
{
  deg4[blockIdx.x * 256 + threadIdx.x] = int4{0, 0, 0, 0};
}

// ---- setup: deg_count (blocks 0..1992) + x->bf16 + W transposes ----
__global__ __launch_bounds__(256) void setup(
    const int* __restrict__ ei, int* __restrict__ deg,
    const float* __restrict__ x, const float* __restrict__ W1,
    const float* __restrict__ Wp, const float* __restrict__ W2,
    ushort* __restrict__ xbf, ushort* __restrict__ w1t,
    ushort* __restrict__ wpt, ushort* __restrict__ w2t)
{
  int b = blockIdx.x;
  int t = threadIdx.x;
  if (b < DEG_BLOCKS) {
    int e = b * 256 + t;
    if (e < ETOT) {
      int d = (e < E_EDGES) ? ei[E_EDGES + e] : (e - E_EDGES);
      atomicAdd(&deg[d], 1);
    }
    return;
  }
  b -= DEG_BLOCKS;
  if (b < 3750) {                       // 3750*256*4 = N*IN
    int i = b * 256 + t;
    float4 v = ((const float4*)x)[i];
    ushort4 o;
    o.x = f2bf(v.x); o.y = f2bf(v.y); o.z = f2bf(v.z); o.w = f2bf(v.w);
    ((ushort4*)xbf)[i] = o;
  } else if (b < 3750 + 128) {
    int k = b - 3750;
    w1t[(size_t)t * IN_DIM + k] = f2bf(W1[(size_t)k * HID + t]);
  } else if (b < 3750 + 256) {
    int k = b - 3878;
    wpt[(size_t)t * IN_DIM + k] = f2bf(Wp[(size_t)k * HID + t]);
  } else {
    int k = b - 4006;
    w2t[(size_t)t * HID + k] = f2bf(W2[(size_t)k * HID + t]);
  }
}

// ================= CSR rowptr scan: shfl wave-scan, 2 syncthreads =================
__global__ __launch_bounds__(1024) void scan_rowptr(const int* __restrict__ deg,
                                                    int* __restrict__ rowptr,
                                                    int* __restrict__ cursor)
{
  const int CE = 30;
  __shared__ int wtot[16];
  __shared__ int wexc[16];
  int t = threadIdx.x;
  int wv = t >> 6, lane = t & 63;
  int base = t * CE;
  int local[CE];
  int s = 0;
  #pragma unroll
  for (int i = 0; i < CE; ++i) {
    int idx = base + i;
    int v = (idx < N_NODES) ? deg[idx] : 0;
    local[i] = s;
    s += v;
  }
  int incl = s;                          // inclusive 64-lane scan
  #pragma unroll
  for (int off = 1; off < 64; off <<= 1) {
    int v = __shfl_up(incl, off);
    if (lane >= off) incl += v;
  }
  if (lane == 63) wtot[wv] = incl;
  __syncthreads();
  if (t < 16) {
    int v = wtot[t];
    int inc2 = v;
    #pragma unroll
    for (int off = 1; off < 16; off <<= 1) {
      int u = __shfl_up(inc2, off);
      if (t >= off) inc2 += u;
    }
    wexc[t] = inc2 - v;
  }
  __syncthreads();
  int off0 = wexc[wv] + (incl - s);      // exclusive thread offset
  #pragma unroll
  for (int i = 0; i < CE; ++i) {
    int idx = base + i;
    if (idx < N_NODES) {
      rowptr[idx] = off0 + local[i];
      cursor[idx] = off0 + local[i];
    }
  }
  if (t == 1023) rowptr[N_NODES] = off0 + s;
}

// ---- standalone edge scatter (low VGPR -> high occupancy for atomic latency) ----
__global__ __launch_bounds__(256) void scatter_edges(const int* __restrict__ ei,
                                                     int* __restrict__ cursor,
                                                     int* __restrict__ col)
{
  int e = blockIdx.x * blockDim.x + threadIdx.x;
  if (e >= ETOT) return;
  int s, d;
  if (e < E_EDGES) { s = ei[e]; d = ei[E_EDGES + e]; }
  else             { s = d = e - E_EDGES; }
  int pos = atomicAdd(&cursor[d], 1);
  col[pos] = s;
}

// ---- LDS-staged bf16 MFMA GEMM (m97-lite) + attn-logit epilogue (+L1 proj) ----
template<int K, bool L1>
__global__ __launch_bounds__(256) void gemm_lds(
    const ushort* __restrict__ A,    // [n][K] bf16
    const ushort* __restrict__ WT,   // [NOUT][K] bf16 (W1t|Wpt contiguous for L1)
    const float* __restrict__ att_src, const float* __restrict__ att_dst,
    unsigned char* __restrict__ hout, float* __restrict__ esrc,
    float* __restrict__ edst, ushort* __restrict__ rout,
    const float* __restrict__ pbias, int n)
{
  __shared__ ushort As[128 * 32];       // [row][pos] 64B/row, 8KB
  __shared__ ushort Bs[128 * 32];
  const int t = threadIdx.x;
  const int wv = t >> 6;
  const int lane = t & 63;
  const int wr = wv >> 1, wc = wv & 1;
  const int brow = blockIdx.x * 128;
  const int bcol0 = blockIdx.y * 128;
  const int lrow = lane & 15;
  const int kgrp = lane >> 4;           // 0..3

  // staging geometry: chunk = wv*128 + i*64 + lane (16B each); row=chunk>>2, pos=chunk&3
  int sc_row[2], sc_kc[2];
  #pragma unroll
  for (int i = 0; i < 2; ++i) {
    int chunk = wv * 128 + i * 64 + lane;
    sc_row[i] = chunk >> 2;
    sc_kc[i] = (chunk & 3) ^ (sc_row[i] & 3);   // pre-swizzled source k-chunk
  }

  f32x4 acc[4][4] = {};
  for (int k0 = 0; k0 < K; k0 += 32) {
    #pragma unroll
    for (int i = 0; i < 2; ++i) {
      int ar = min(brow + sc_row[i], n - 1);
      gload_lds16(&A[(size_t)ar * K + k0 + sc_kc[i] * 8],
                  &As[(size_t)(wv * 2 + i) * 512]);
      int bc = bcol0 + sc_row[i];
      gload_lds16(&WT[(size_t)bc * K + k0 + sc_kc[i] * 8],
                  &Bs[(size_t)(wv * 2 + i) * 512]);
    }
    __syncthreads();                    // drains vmcnt+lgkmcnt (compiler-inserted)
    bf16x8 a[4], b[4];
    #pragma unroll
    for (int mi = 0; mi < 4; ++mi) {
      int tr = wr * 64 + mi * 16 + lrow;
      int pos = kgrp ^ (tr & 3);
      a[mi] = *(const bf16x8*)&As[tr * 32 + pos * 8];
    }
    #pragma unroll
    for (int ni = 0; ni < 4; ++ni) {
      int tc = wc * 64 + ni * 16 + lrow;
      int pos = kgrp ^ (tc & 3);
      b[ni] = *(const bf16x8*)&Bs[tc * 32 + pos * 8];
    }
    #pragma unroll
    for (int mi = 0; mi < 4; ++mi)
      #pragma unroll
      for (int ni = 0; ni < 4; ++ni)
        acc[mi][ni] = __builtin_amdgcn_mfma_f32_16x16x32_bf16(a[mi], b[ni], acc[mi][ni], 0, 0, 0);
    __syncthreads();                    // before restage
  }

  const int bcol = bcol0 + wc * 64;
  const bool proj = L1 && (bcol >= 256);
  // C write (C/D layout: col=lane&15, row=(lane>>4)*4+reg — m89-verified)
  const int browt = brow + wr * 64;
  #pragma unroll
  for (int mi = 0; mi < 4; ++mi) {
    #pragma unroll
    for (int r = 0; r < 4; ++r) {
      int row = browt + mi * 16 + kgrp * 4 + r;
      if (row < n) {
        #pragma unroll
        for (int ni = 0; ni < 4; ++ni) {
          int colg = bcol + ni * 16 + lrow;
          float v = acc[mi][ni][r];
          if (proj) {
            int c = colg - 256;
            rout[(size_t)row * HID + c] = f2bf(v + pbias[c]);
          } else {
            hout[(size_t)row * HID + colg] = f2fp8(v);
          }
        }
      }
    }
  }
  // fused attention-logit epilogue: wave's 64 cols == head (bcol>>6)
  if (!proj) {
    const int hh = bcol >> 6;
    float as[4], ad[4];
    #pragma unroll
    for (int ni = 0; ni < 4; ++ni) {
      as[ni] = att_src[hh * 64 + ni * 16 + lrow];
      ad[ni] = att_dst[hh * 64 + ni * 16 + lrow];
    }
    #pragma unroll
    for (int mi = 0; mi < 4; ++mi) {
      #pragma unroll
      for (int r = 0; r < 4; ++r) {
        float vs = 0.f, vd = 0.f;
        #pragma unroll
        for (int ni = 0; ni < 4; ++ni) {
          float c = acc[mi][ni][r];
          vs += c * as[ni];
          vd += c * ad[ni];
        }
        #pragma unroll
        for (int m = 1; m <= 8; m <<= 1) {
          vs += __shfl_xor(vs, m);
          vd += __shfl_xor(vd, m);
        }
        int row = browt + mi * 16 + kgrp * 4 + r;
        if (lrow == 0 && row < n) {
          esrc[row * HEADS + hh] = vs;
          edst[row * HEADS + hh] = vd;
        }
      }
    }
  }
}

// ========== aggregation: one 16-LANE GROUP per dst node ==========
// __launch_bounds__(256,4): ~128 VGPR budget so all 8 h-gathers + 8 esrc
// gathers stay in flight (R12's 32-VGPR build serialized the window).
// Full-8 chunks are guard-free; masked tail chunk handles deg%8.
// R18's explicit A/B ping-pong REGRESSED (VGPR 84, occ 22.6%, +20us) —
// straight-line chunks + wave TLP is the verified optimum here.
template<bool WRITE_BF16>
__global__ __launch_bounds__(256, 4) void gat_agg(
    const int* __restrict__ rowptr, const int* __restrict__ col,
    const float* __restrict__ esrc, const float* __restrict__ edst,
    const unsigned char* __restrict__ h8, const float* __restrict__ bias,
    const ushort* __restrict__ resid, const float* __restrict__ gamma,
    const float* __restrict__ beta, float* __restrict__ out_f32,
    ushort* __restrict__ out_bf16)
{
  const int t = threadIdx.x;
  const int lane16 = t & 15;                   // channel sub-block within group
  const int d = blockIdx.x * 16 + (t >> 4);    // grid = 1875 exact
  const int cblk = lane16 * 16;                // 16 fp8 channels
  const int headc = lane16 >> 2;               // head of these channels
  const int r0 = rowptr[d], r1 = rowptr[d + 1];

  // hoisted independent loads (overlap under the gather loop)
  const uint4* rp = (const uint4*)&resid[(size_t)d * HID + cblk];
  uint4 r0v = rp[0], r1v = rp[1];
  const float edh = edst[d * HEADS + headc];

  f32x2 acc2[8] = {};                          // 16 channels
  float dp = 0.f;

  int j = r0;
  // ---- full 8-edge chunks: no guards, 16 independent gathers in flight ----
  for (; j + 8 <= r1; j += 8) {
    int s[8];
    #pragma unroll
    for (int i = 0; i < 8; ++i) s[i] = col[j + i];
    float es[8];
    #pragma unroll
    for (int i = 0; i < 8; ++i) es[i] = esrc[s[i] * HEADS + headc];
    uint4 w[8];
    #pragma unroll
    for (int i = 0; i < 8; ++i)
      w[i] = *(const uint4*)&h8[(size_t)s[i] * HID + cblk];
    #pragma unroll
    for (int i = 0; i < 8; ++i) {
      float v = es[i] + edh;
      v = (v >= 0.f) ? v : NEG_SLOPE * v;
      float p = __expf(v);                     // max-free exp: validated R4-R17
      dp += p;
      f32x2 p2 = { p, p };
      unsigned wd0 = w[i].x, wd1 = w[i].y, wd2 = w[i].z, wd3 = w[i].w;
      acc2[0] += __builtin_amdgcn_cvt_pk_f32_fp8(wd0, false) * p2;
      acc2[1] += __builtin_amdgcn_cvt_pk_f32_fp8(wd0, true)  * p2;
      acc2[2] += __builtin_amdgcn_cvt_pk_f32_fp8(wd1, false) * p2;
      acc2[3] += __builtin_amdgcn_cvt_pk_f32_fp8(wd1, true)  * p2;
      acc2[4] += __builtin_amdgcn_cvt_pk_f32_fp8(wd2, false) * p2;
      acc2[5] += __builtin_amdgcn_cvt_pk_f32_fp8(wd2, true)  * p2;
      acc2[6] += __builtin_amdgcn_cvt_pk_f32_fp8(wd3, false) * p2;
      acc2[7] += __builtin_amdgcn_cvt_pk_f32_fp8(wd3, true)  * p2;
    }
  }
  // ---- masked tail (0..7 edges) ----
  if (j < r1) {
    int s[8];
    #pragma unroll
    for (int i = 0; i < 8; ++i) s[i] = col[min(j + i, r1 - 1)];
    float es[8];
    #pragma unroll
    for (int i = 0; i < 8; ++i) es[i] = esrc[s[i] * HEADS + headc];
    uint4 w[8];
    #pragma unroll
    for (int i = 0; i < 8; ++i)
      w[i] = *(const uint4*)&h8[(size_t)s[i] * HID + cblk];
    #pragma unroll
    for (int i = 0; i < 8; ++i) {
      float v = es[i] + edh;
      v = (v >= 0.f) ? v : NEG_SLOPE * v;
      float p = (j + i < r1) ? __expf(v) : 0.f;
      dp += p;
      f32x2 p2 = { p, p };
      unsigned wd0 = w[i].x, wd1 = w[i].y, wd2 = w[i].z, wd3 = w[i].w;
      acc2[0] += __builtin_amdgcn_cvt_pk_f32_fp8(wd0, false) * p2;
      acc2[1] += __builtin_amdgcn_cvt_pk_f32_fp8(wd0, true)  * p2;
      acc2[2] += __builtin_amdgcn_cvt_pk_f32_fp8(wd1, false) * p2;
      acc2[3] += __builtin_amdgcn_cvt_pk_f32_fp8(wd1, true)  * p2;
      acc2[4] += __builtin_amdgcn_cvt_pk_f32_fp8(wd2, false) * p2;
      acc2[5] += __builtin_amdgcn_cvt_pk_f32_fp8(wd2, true)  * p2;
      acc2[6] += __builtin_amdgcn_cvt_pk_f32_fp8(wd3, false) * p2;
      acc2[7] += __builtin_amdgcn_cvt_pk_f32_fp8(wd3, true)  * p2;
    }
  }

  float rden = 1.f / dp;                       // per-head denom, group-uniform

  // v = agg/den + bias + resid (16 channels per lane)
  f32x2 v2[8];
  {
    unsigned rd[8] = { r0v.x, r0v.y, r0v.z, r0v.w, r1v.x, r1v.y, r1v.z, r1v.w };
    const f32x2* b2 = (const f32x2*)&bias[cblk];
    f32x2 rden2 = { rden, rden };
    #pragma unroll
    for (int q = 0; q < 8; ++q) {
      f32x2 rw;
      rw.x = __uint_as_float(rd[q] << 16);
      rw.y = __uint_as_float(rd[q] & 0xffff0000u);
      v2[q] = acc2[q] * rden2 + b2[q] + rw;
    }
  }

  // LayerNorm stats over the 16-lane group (each channel once) -> /256
  float s1 = 0.f, s2 = 0.f;
  #pragma unroll
  for (int q = 0; q < 8; ++q) {
    s1 += v2[q].x + v2[q].y;
    s2 += v2[q].x * v2[q].x + v2[q].y * v2[q].y;
  }
  #pragma unroll
  for (int m = 1; m <= 8; m <<= 1) {
    s1 += __shfl_xor(s1, m);
    s2 += __shfl_xor(s2, m);
  }
  float mu = s1 * (1.f / HID);
  float var = s2 * (1.f / HID) - mu * mu;
  float rr = rsqrtf(var + 1e-5f);

  const f32x2* g2 = (const f32x2*)&gamma[cblk];
  const f32x2* e2 = (const f32x2*)&beta[cblk];
  float y[16];
  #pragma unroll
  for (int q = 0; q < 8; ++q) {
    f32x2 g = g2[q], e = e2[q];
    float t0 = (v2[q].x - mu) * rr * g.x + e.x;
    float t1 = (v2[q].y - mu) * rr * g.y + e.y;
    y[2 * q]     = (t0 > 0.f) ? t0 : expm1f(t0);
    y[2 * q + 1] = (t1 > 0.f) ? t1 : expm1f(t1);
  }
  if (WRITE_BF16) {
    uint4 o[2];
    #pragma unroll
    for (int q = 0; q < 8; ++q) {
      unsigned wv = (unsigned)f2bf(y[2 * q]) | ((unsigned)f2bf(y[2 * q + 1]) << 16);
      ((unsigned*)o)[q] = wv;
    }
    uint4* op = (uint4*)&out_bf16[(size_t)d * HID + cblk];
    op[0] = o[0]; op[1] = o[1];
  } else {
    float4* op = (float4*)&out_f32[(size_t)d * HID + cblk];
    #pragma unroll
    for (int q = 0; q < 4; ++q) {
      float4 ov = { y[4 * q], y[4 * q + 1], y[4 * q + 2], y[4 * q + 3] };
      op[q] = ov;
    }
  }
}

extern "C" void kernel_launch(void* const* d_in, const int* in_sizes, int n_in,
                              void* d_out, int out_size, void* d_ws, size_t ws_size,
                              hipStream_t stream) {
  const float* x   = (const float*)d_in[0];
  const int*   ei  = (const int*)d_in[1];
  const float* W1  = (const float*)d_in[2];
  const float* as1 = (const float*)d_in[3];
  const float* ad1 = (const float*)d_in[4];
  const float* b1  = (const float*)d_in[5];
  const float* W2  = (const float*)d_in[6];
  const float* as2 = (const float*)d_in[7];
  const float* ad2 = (const float*)d_in[8];
  const float* b2  = (const float*)d_in[9];
  const float* g1  = (const float*)d_in[10];
  const float* be1 = (const float*)d_in[11];
  const float* g2  = (const float*)d_in[12];
  const float* be2 = (const float*)d_in[13];
  const float* Wp  = (const float*)d_in[14];
  const float* bp  = (const float*)d_in[15];
  float* out = (float*)d_out;

  const size_t NB16 = (size_t)N_NODES * HID * sizeof(ushort);  // 15.36 MB
  const size_t NB8  = (size_t)N_NODES * HID;                   // 7.68 MB (fp8)
  const size_t XB16 = (size_t)N_NODES * IN_DIM * sizeof(ushort);
  const size_t NH_BUF = (size_t)N_NODES * HEADS * sizeof(float);
  char* ws = (char*)d_ws;
  size_t off = 0;
  unsigned char* h8 = (unsigned char*)(ws + off); off += NB8;  // h gather table (fp8)
  ushort* hAbf  = (ushort*)(ws + off); off += NB16;            // hA / layer-2 resid
  ushort* rbf   = (ushort*)(ws + off); off += NB16;            // layer-1 resid (bf16)
  ushort* xbf   = (ushort*)(ws + off); off += XB16;
  ushort* w1t   = (ushort*)(ws + off); off += (size_t)HID * IN_DIM * 2;  // [w1t|wpt]
  ushort* wpt   = (ushort*)(ws + off); off += (size_t)HID * IN_DIM * 2;
  ushort* w2t   = (ushort*)(ws + off); off += (size_t)HID * HID * 2;
  float*  esrc  = (float*) (ws + off); off += NH_BUF;
  float*  edstb = (float*) (ws + off); off += NH_BUF;
  int*    deg    = (int*)(ws + off); off += (size_t)30720 * 4;  // padded for int4 zero
  int*    rowptr = (int*)(ws + off); off += (size_t)(N_NODES + 1) * 4;
  int*    cursor = (int*)(ws + off); off += (size_t)N_NODES * 4;
  int*    col    = (int*)(ws + off); off += (size_t)ETOT * 4;

  // ---- CSR build + precision prep ----
  zero_deg<<<30, 256, 0, stream>>>((int4*)deg);
  setup<<<DEG_BLOCKS + 3750 + 128 + 128 + 256, 256, 0, stream>>>(
      ei, deg, x, W1, Wp, W2, xbf, w1t, wpt, w2t);
  scan_rowptr<<<1, 1024, 0, stream>>>(deg, rowptr, cursor);
  scatter_edges<<<cdiv(ETOT, 256), 256, 0, stream>>>(ei, cursor, col);

  // ================= Layer 1 (W1 and Wp fused: 512 output cols) =================
  gemm_lds<IN_DIM, true><<<dim3(cdiv(N_NODES, 128), 4), 256, 0, stream>>>(
      xbf, w1t, as1, ad1, h8, esrc, edstb, rbf, bp, N_NODES);
  gat_agg<true><<<N_NODES / 16, 256, 0, stream>>>(
      rowptr, col, esrc, edstb, h8, b1, rbf, g1, be1, nullptr, hAbf);

  // ================= Layer 2 =================
  gemm_lds<HID, false><<<dim3(cdiv(N_NODES, 128), 2), 256, 0, stream>>>(
      hAbf, w2t, as2, ad2, h8, esrc, edstb, nullptr, nullptr, N_NODES);
  gat_agg<false><<<N_NODES / 16, 256, 0, stream>>>(
      rowptr, col, esrc, edstb, h8, b2, hAbf, g2, be2, out, nullptr);
}